// Round 4
// baseline (149.992 us; speedup 1.0000x reference)
//
#include <hip/hip_runtime.h>

// LlamaAttention — Round 11: m201 8-phase 256^2 template (T3+T4+T5+T2).
//
// out = x @ (Wo @ Wv)^T  (softmax == I, established r0-r10).
// r8/r9/r10 all ~54 us with MfmaUtil 13% — the shared invariant is the
// coarse one-phase K-step (stage/barrier/MFMA lockstep). Catalog: T2/T4/T5
// are null on that structure; the lever is the 8-phase fine interleave.
// This round: 256x256 tile, BK=64, 8 waves (2Mx4N, wave=128x64 as 2x2
// strips), dbuf 128KB LDS, 192 blocks (1/CU). Per phase: 12 ds_read_b128
// (quadrant frags) | stage 1 half-tile | vmcnt(6) | barrier | 16 MFMA
// (setprio) | barrier. B via global_load_lds from prep-swizzled wt
// (8-chunk XOR key=row&7 — the r9-proven conflict-free one). A (fp32 x)
// reg-staged with issue-early/cvt-late (T14): issue ph p, cvt+ds_write
// ph p+2, consume ph p+4. Per-wave vmcnt FIFO traced: uniform vmcnt(6)
// steady-state; prologue vmcnt(8)/(6); tail (6,6,6,6,2,2,0,0).

typedef unsigned short u16;
typedef __attribute__((ext_vector_type(8))) short short8;      // 16 B
typedef __attribute__((ext_vector_type(8))) _Float16 f16x8;    // 4 VGPR MFMA frag
typedef __attribute__((ext_vector_type(4))) float float4v;

__device__ inline u16 f16b(float f) {
  union { _Float16 h; u16 u; } v; v.h = (_Float16)f; return v.u;  // v_cvt_f16_f32 RNE
}

__device__ inline u16 f32_to_bf16(float f) {        // fallback path only
  union { float f; unsigned int u; } v; v.f = f;
  unsigned int r = v.u + 0x7FFF + ((v.u >> 16) & 1);
  return (u16)(r >> 16);
}

__device__ inline void gld_lds16(const u16* g, u16* l) {
  auto gp = (const __attribute__((address_space(1))) unsigned int*)(g);
  auto lp = (__attribute__((address_space(3))) unsigned int*)(l);
  __builtin_amdgcn_global_load_lds(gp, lp, 16, 0, 0);
}

// ---------------- prep: W = Wo @ Wv, fp32 accum, f16 tiled+swizzled -------
// wt image per (nt, kt, half): [col 128][chunk 8][8 f16], where
// image[col][c] = W[o = nt*256+half*128+col][k = kt*64 + (c ^ (col&7))*8 ..].
// Same compute/numerics as r9/r10 (k ascending, fp32 fma, f16 RNE store).
__global__ __launch_bounds__(256)
void prep_w(const float* __restrict__ Wv, const float* __restrict__ Wo,
            u16* __restrict__ wt) {
  __shared__ __align__(16) float wo[4][256];            // 4 KB
  const int og = blockIdx.x / 3, hc = blockIdx.x % 3;
  const int o0 = og * 4;
  ((float4v*)&wo[0][0])[threadIdx.x] =
      ((const float4v*)(Wo + (size_t)o0 * 256))[threadIdx.x];
  __syncthreads();
  const int h = hc * 256 + threadIdx.x;
  float acc[4] = {0.f, 0.f, 0.f, 0.f};
  for (int k = 0; k < 256; k += 8) {
    float wv[8];
#pragma unroll
    for (int u = 0; u < 8; ++u) wv[u] = Wv[(size_t)(k + u) * 768 + h];
#pragma unroll
    for (int j = 0; j < 4; ++j) {
      float4v c0 = *(const float4v*)(&wo[j][k]);
      float4v c1 = *(const float4v*)(&wo[j][k + 4]);
      acc[j] = fmaf(c0[0], wv[0], acc[j]);
      acc[j] = fmaf(c0[1], wv[1], acc[j]);
      acc[j] = fmaf(c0[2], wv[2], acc[j]);
      acc[j] = fmaf(c0[3], wv[3], acc[j]);
      acc[j] = fmaf(c1[0], wv[4], acc[j]);
      acc[j] = fmaf(c1[1], wv[5], acc[j]);
      acc[j] = fmaf(c1[2], wv[6], acc[j]);
      acc[j] = fmaf(c1[3], wv[7], acc[j]);
    }
  }
  const int kt = h >> 6, c6 = (h >> 3) & 7, e = h & 7;
#pragma unroll
  for (int j = 0; j < 4; ++j) {
    const int o = o0 + j;
    const int nto = o >> 8, half = (o >> 7) & 1, col = o & 127;
    wt[((((size_t)(nto * 12 + kt) * 2 + half) * 128 + col) * 8 +
        (c6 ^ (col & 7))) * 8 + e] = f16b(acc[j]);
  }
}

// ---------------- main: out[16384,768] = x @ W^T, 8-phase template --------
// LDS map (u16 units): A buf c at c*16384 (256 rows x 64), B at 32768 +
// c*16384 (256 cols x 64). Row layout: [row][chunk 8][8], chunk stored =
// global_chunk ^ (row&7).
__global__ __launch_bounds__(512, 2)
void gemm_xw(const float* __restrict__ x, const u16* __restrict__ wt,
             float* __restrict__ out) {
  __shared__ __align__(16) u16 S[65536];          // 128 KB -> 1 block/CU

  const int tid = threadIdx.x;
  const int w = tid >> 6, l = tid & 63;
  const int q = l >> 4, mr = l & 15;
  const int wm = w & 1, wn = w >> 1;              // 2 (M) x 4 (N) waves

  // 192 blocks = 8 XCD x 24; A-panels (same mt, 3 nt) XCD-local.
  const int sb = (blockIdx.x & 7) * 24 + (blockIdx.x >> 3);
  const int mt = sb / 3, nt = sb - mt * 3;
  const int row0 = mt * 256, col0 = nt * 256;

  // A staging: thread -> row tid>>2 (0..127 within half), 16 f32 at (tid&3)*16
  const int arow = tid >> 2, t2 = (tid & 3) << 1;  // chunk pair {2t, 2t+1}
  const float* xg = x + (size_t)(row0 + arow) * 768 + (t2 << 3);
  const int akey = arow & 7;
  const int aw0 = arow * 64 + (((t2    ) ^ akey) << 3);
  const int aw1 = arow * 64 + (((t2 + 1) ^ akey) << 3);

  // B staging source (image is exact LDS order): + T*16384 + h*8192
  const u16* wtb = wt + (size_t)nt * 196608 + tid * 8;

  // Operand frag bases (per-lane): global chunk ck = kk*4+q at LDS chunk
  // ck ^ (mr&7); row/col runtime part is (wm*64+mr) / (wn*32+mr).
  const int lkey = mr & 7;
  const u16* Ab0 = S + (wm * 64 + mr) * 64 + (((q    ) ^ lkey) << 3);
  const u16* Ab1 = S + (wm * 64 + mr) * 64 + (((4 + q) ^ lkey) << 3);
  const u16* Bb0 = S + 32768 + (wn * 32 + mr) * 64 + (((q    ) ^ lkey) << 3);
  const u16* Bb1 = S + 32768 + (wn * 32 + mr) * 64 + (((4 + q) ^ lkey) << 3);

  float4v acc[8][4];
#pragma unroll
  for (int i = 0; i < 8; ++i)
#pragma unroll
    for (int j = 0; j < 4; ++j) acc[i][j] = (float4v){0.f, 0.f, 0.f, 0.f};

  float4v ae0, ae1, ae2, ae3;   // A reg set "even" slots
  float4v ao0, ao1, ao2, ao3;   // A reg set "odd" slots

#define ISSUE_A(r0_, r1_, r2_, r3_, T, h)                                    \
  { const float* p = xg + (size_t)(h) * 98304 + (size_t)(T) * 64;            \
    r0_ = *(const float4v*)(p);      r1_ = *(const float4v*)(p + 4);         \
    r2_ = *(const float4v*)(p + 8);  r3_ = *(const float4v*)(p + 12); }

#define CVT_A(r0_, r1_, r2_, r3_, cbuf, h)                                   \
  { union { u16 hh[8]; short8 s8; } p0, p1;                                  \
    _Pragma("unroll")                                                        \
    for (int e = 0; e < 4; ++e) {                                            \
      p0.hh[e] = f16b(r0_[e]); p0.hh[e + 4] = f16b(r1_[e]);                  \
      p1.hh[e] = f16b(r2_[e]); p1.hh[e + 4] = f16b(r3_[e]);                  \
    }                                                                        \
    u16* d = S + (cbuf) * 16384 + (h) * 8192;                                \
    *(short8*)(d + aw0) = p0.s8;                                             \
    *(short8*)(d + aw1) = p1.s8; }

#define ISSUE_B(T, h)                                                        \
  { const u16* g = wtb + (size_t)(T) * 16384 + (h) * 8192;                   \
    u16* d = S + 32768 + ((T) & 1) * 16384 + (h) * 8192 + tid * 8;           \
    gld_lds16(g, d); gld_lds16(g + 4096, d + 4096); }

// One phase: frag reads | stage | vmcnt(N) | cvt | lgkm(0) | barrier |
// MFMA quadrant (S_,U_) of buf cbuf | barrier.
#define PHASE(cbuf, S_, U_, STAGE, WAITN, CVT)                               \
  { f16x8 av[4][2], bv[2][2];                                                \
    _Pragma("unroll")                                                        \
    for (int im = 0; im < 4; ++im) {                                         \
      av[im][0] = *(const f16x8*)(Ab0 + (cbuf) * 16384 + ((S_) * 128 + im * 16) * 64); \
      av[im][1] = *(const f16x8*)(Ab1 + (cbuf) * 16384 + ((S_) * 128 + im * 16) * 64); \
    }                                                                        \
    _Pragma("unroll")                                                        \
    for (int jn = 0; jn < 2; ++jn) {                                         \
      bv[jn][0] = *(const f16x8*)(Bb0 + (cbuf) * 16384 + ((U_) * 128 + jn * 16) * 64); \
      bv[jn][1] = *(const f16x8*)(Bb1 + (cbuf) * 16384 + ((U_) * 128 + jn * 16) * 64); \
    }                                                                        \
    STAGE;                                                                   \
    asm volatile("s_waitcnt vmcnt(" #WAITN ")" ::: "memory");                \
    CVT;                                                                     \
    asm volatile("s_waitcnt lgkmcnt(0)" ::: "memory");                       \
    __builtin_amdgcn_s_barrier();                                            \
    __builtin_amdgcn_s_setprio(1);                                           \
    _Pragma("unroll")                                                        \
    for (int kk = 0; kk < 2; ++kk)                                           \
      _Pragma("unroll")                                                      \
      for (int im = 0; im < 4; ++im)                                         \
        _Pragma("unroll")                                                    \
        for (int jn = 0; jn < 2; ++jn)                                       \
          acc[(S_) * 4 + im][(U_) * 2 + jn] = __builtin_amdgcn_mfma_f32_16x16x32_f16( \
              av[im][kk], bv[jn][kk], acc[(S_) * 4 + im][(U_) * 2 + jn], 0, 0, 0); \
    __builtin_amdgcn_s_setprio(0);                                           \
    __builtin_amdgcn_s_barrier(); }

  // ---- prologue: tile 0 = [A0, B0, A1, B1]; retire {A0,B0}; cvt A0 ----
  ISSUE_A(ae0, ae1, ae2, ae3, 0, 0);
  ISSUE_B(0, 0);
  ISSUE_A(ao0, ao1, ao2, ao3, 0, 1);
  ISSUE_B(0, 1);
  asm volatile("s_waitcnt vmcnt(8)" ::: "memory");   // A0(0) retired
  CVT_A(ae0, ae1, ae2, ae3, 0, 0);                   // -> buf0.half0
  asm volatile("s_waitcnt vmcnt(6)" ::: "memory");   // B0(0) retired
  asm volatile("s_waitcnt lgkmcnt(0)" ::: "memory");
  __builtin_amdgcn_s_barrier();
  // outstanding: [A1(0)x4, B1(0)x2] = 6  (steady-state entry invariant)

  // ---- steady: iterations t = 0,2,4,6,8 (tiles t, t+1) ----
  for (int t = 0; t < 10; t += 2) {
    PHASE(0, 0, 0, ISSUE_A(ae0, ae1, ae2, ae3, t + 1, 0), 6,
          CVT_A(ao0, ao1, ao2, ao3, 0, 1))                  // cvt A1(t)->buf0.h1
    PHASE(0, 1, 0, ISSUE_B(t + 1, 0), 6, )
    PHASE(0, 0, 1, ISSUE_A(ao0, ao1, ao2, ao3, t + 1, 1), 6,
          CVT_A(ae0, ae1, ae2, ae3, 1, 0))                  // cvt A0(t+1)->buf1.h0
    PHASE(0, 1, 1, ISSUE_B(t + 1, 1), 6, )
    PHASE(1, 0, 0, ISSUE_A(ae0, ae1, ae2, ae3, t + 2, 0), 6,
          CVT_A(ao0, ao1, ao2, ao3, 1, 1))                  // cvt A1(t+1)->buf1.h1
    PHASE(1, 1, 0, ISSUE_B(t + 2, 0), 6, )
    PHASE(1, 0, 1, ISSUE_A(ao0, ao1, ao2, ao3, t + 2, 1), 6,
          CVT_A(ae0, ae1, ae2, ae3, 0, 0))                  // cvt A0(t+2)->buf0.h0
    PHASE(1, 1, 1, ISSUE_B(t + 2, 1), 6, )
  }

  // ---- tail: tiles 10, 11 (stage 11 in ph0-3; drain in ph4-7) ----
  PHASE(0, 0, 0, ISSUE_A(ae0, ae1, ae2, ae3, 11, 0), 6,
        CVT_A(ao0, ao1, ao2, ao3, 0, 1))                    // cvt A1(10)
  PHASE(0, 1, 0, ISSUE_B(11, 0), 6, )
  PHASE(0, 0, 1, ISSUE_A(ao0, ao1, ao2, ao3, 11, 1), 6,
        CVT_A(ae0, ae1, ae2, ae3, 1, 0))                    // cvt A0(11)
  PHASE(0, 1, 1, ISSUE_B(11, 1), 6, )
  PHASE(1, 0, 0, , 2, CVT_A(ao0, ao1, ao2, ao3, 1, 1))      // cvt A1(11)
  PHASE(1, 1, 0, , 2, )
  PHASE(1, 0, 1, , 0, )                                     // B1(11) retired
  PHASE(1, 1, 1, , 0, )

#undef ISSUE_A
#undef CVT_A
#undef ISSUE_B
#undef PHASE

  // ---- epilogue: C/D col=lane&15, row=q*4+reg (m89-verified) ----
#pragma unroll
  for (int s = 0; s < 2; ++s)
#pragma unroll
    for (int im = 0; im < 4; ++im)
#pragma unroll
      for (int u = 0; u < 2; ++u)
#pragma unroll
        for (int jn = 0; jn < 2; ++jn) {
          const int r0 = row0 + s * 128 + wm * 64 + im * 16 + q * 4;
          const int c  = col0 + u * 128 + wn * 32 + jn * 16 + mr;
#pragma unroll
          for (int r = 0; r < 4; ++r)
            out[(size_t)(r0 + r) * 768 + c] = acc[s * 4 + im][u * 2 + jn][r];
        }
}

// ---------------- fallback (no workspace): verified r7 kernel ----------------
__global__ __launch_bounds__(512, 1)
void fused_fallback(const float* __restrict__ x,
                    const float* __restrict__ Wv, const float* __restrict__ Wo,
                    float* __restrict__ out) {
  __shared__ __align__(16) u16 As[64 * 32];
  __shared__ __align__(16) u16 Bs[256 * 32];
  __shared__ __align__(16) u16 Vs[64 * 264];

  const int tid = threadIdx.x;
  const int w  = tid >> 6, l = tid & 63;
  const int q  = l >> 4, mr = l & 15;
  const int wm = w & 1, wn = w >> 1;
  const int row0 = blockIdx.x * 64;
  const int xr = tid >> 3, xg = (tid & 7) * 4;
  const int wr = tid >> 1, wh = (tid & 1) * 16;

  float4v acc[2][4];
#pragma unroll
  for (int i = 0; i < 2; ++i)
#pragma unroll
    for (int j = 0; j < 4; ++j) acc[i][j] = (float4v){0.f, 0.f, 0.f, 0.f};

  for (int kt = 0; kt < 24; ++kt) {
    const int k0 = kt * 32;
    {
      float4v v = *(const float4v*)(x + (size_t)(row0 + xr) * 768 + k0 + xg);
      union { u16 h[4]; uint2 u; } p;
      p.h[0] = f32_to_bf16(v[0]); p.h[1] = f32_to_bf16(v[1]);
      p.h[2] = f32_to_bf16(v[2]); p.h[3] = f32_to_bf16(v[3]);
      *(uint2*)(As + xr * 32 + xg) = p.u;
    }
    {
      const float* g = Wv + (size_t)wr * 768 + k0 + wh;
      union { u16 h[16]; short8 s[2]; } p;
#pragma unroll
      for (int u = 0; u < 4; ++u) {
        float4v v = *(const float4v*)(g + u * 4);
        p.h[u * 4 + 0] = f32_to_bf16(v[0]); p.h[u * 4 + 1] = f32_to_bf16(v[1]);
        p.h[u * 4 + 2] = f32_to_bf16(v[2]); p.h[u * 4 + 3] = f32_to_bf16(v[3]);
      }
      *(short8*)(Bs + wr * 32 + wh) = p.s[0];
      *(short8*)(Bs + wr * 32 + wh + 8) = p.s[1];
    }
    __syncthreads();

    short8 a[2], b[4];
#pragma unroll
    for (int i = 0; i < 2; ++i)
      a[i] = *(const short8*)(As + (wm * 32 + i * 16 + mr) * 32 + q * 8);
#pragma unroll
    for (int j = 0; j < 4; ++j)
      b[j] = *(const short8*)(Bs + (wn * 64 + j * 16 + mr) * 32 + q * 8);
#pragma unroll
    for (int i = 0; i < 2; ++i)
#pragma unroll
      for (int j = 0; j < 4; ++j)
        acc[i][j] = __builtin_amdgcn_mfma_f32_16x16x32_bf16(a[i], b[j], acc[i][j], 0, 0, 0);
    __syncthreads();
  }

#pragma unroll
  for (int i = 0; i < 2; ++i)
#pragma unroll
    for (int j = 0; j < 4; ++j) {
      int row = wm * 32 + i * 16 + q * 4;
      int col = wn * 64 + j * 16 + mr;
#pragma unroll
      for (int r = 0; r < 4; ++r)
        Vs[(row + r) * 264 + col] = f32_to_bf16(acc[i][j][r]);
    }
  __syncthreads();

  for (int c = 0; c < 3; ++c) {
    float4v acc2[2][4];
#pragma unroll
    for (int i = 0; i < 2; ++i)
#pragma unroll
      for (int j = 0; j < 4; ++j) acc2[i][j] = (float4v){0.f, 0.f, 0.f, 0.f};

    for (int kt = 0; kt < 8; ++kt) {
      const int k0 = kt * 32;
      {
        const float* g = Wo + (size_t)(c * 256 + wr) * 256 + k0 + wh;
        union { u16 h[16]; short8 s[2]; } p;
#pragma unroll
        for (int u = 0; u < 4; ++u) {
          float4v v = *(const float4v*)(g + u * 4);
          p.h[u * 4 + 0] = f32_to_bf16(v[0]); p.h[u * 4 + 1] = f32_to_bf16(v[1]);
          p.h[u * 4 + 2] = f32_to_bf16(v[2]); p.h[u * 4 + 3] = f32_to_bf16(v[3]);
        }
        *(short8*)(Bs + wr * 32 + wh) = p.s[0];
        *(short8*)(Bs + wr * 32 + wh + 8) = p.s[1];
      }
      __syncthreads();

      short8 a[2], b[4];
#pragma unroll
      for (int i = 0; i < 2; ++i)
        a[i] = *(const short8*)(Vs + (wm * 32 + i * 16 + mr) * 264 + k0 + q * 8);
#pragma unroll
      for (int j = 0; j < 4; ++j)
        b[j] = *(const short8*)(Bs + (wn * 64 + j * 16 + mr) * 32 + q * 8);
#pragma unroll
      for (int i = 0; i < 2; ++i)
#pragma unroll
        for (int j = 0; j < 4; ++j)
          acc2[i][j] = __builtin_amdgcn_mfma_f32_16x16x32_bf16(a[i], b[j], acc2[i][j], 0, 0, 0);
      __syncthreads();
    }

#pragma unroll
    for (int i = 0; i < 2; ++i)
#pragma unroll
      for (int j = 0; j < 4; ++j) {
        int row = row0 + wm * 32 + i * 16 + q * 4;
        int col = c * 256 + wn * 64 + j * 16 + mr;
#pragma unroll
        for (int r = 0; r < 4; ++r)
          out[(size_t)(row + r) * 768 + col] = acc2[i][j][r];
      }
  }
}

extern "C" void kernel_launch(void* const* d_in, const int* in_sizes, int n_in,
                              void* d_out, int out_size, void* d_ws, size_t ws_size,
                              hipStream_t stream) {
  (void)in_sizes; (void)n_in; (void)out_size;
  const float* x  = (const float*)d_in[0];  // [16384, 768]
  const float* Wv = (const float*)d_in[3];  // [256, 768]
  const float* Wo = (const float*)d_in[4];  // [768, 256]
  float* out = (float*)d_out;

  if (ws_size >= (size_t)768 * 768 * 2) {   // 1.18 MB f16 combined weight
    u16* wt = (u16*)d_ws;
    prep_w<<<dim3(576), dim3(256), 0, stream>>>(Wv, Wo, wt);
    gemm_xw<<<dim3(192), dim3(512), 0, stream>>>(x, wt, out);
  } else {
    fused_fallback<<<dim3(256), dim3(512), 0, stream>>>(x, Wv, Wo, out);
  }
}

// Round 5
// 130.276 us; speedup vs baseline: 1.1513x; 1.1513x over previous
//
#include <hip/hip_runtime.h>

// LlamaAttention — Round 12: barrier-free streaming GEMM.
//
// out = x @ (Wo @ Wv)^T  (softmax == I, established r0-r11).
// r8-r11 post-mortem: FIVE different schedules all ~54 us, all pipes <20%.
// Shared invariant: barrier-lockstep LDS staging -> in-flight window
// collapses at every barrier -> latency-bound ~1.5 TB/s on ~80 MB.
// This round inverts the structure: W (768x768 f16 = 1.18 MB) is
// L2-resident, so stage x (64 rows x 768 K = 96 KB f16) in LDS ONCE,
// then a ZERO-BARRIER K-loop: A-frags from LDS, B-frags global->VGPR
// straight from L2 (pre-tiled wt, 1 KB/instr coalesced), explicit
// 1-step-ahead double-buffer (named a0/a1/b0/b1 — rule #20). 8 waves x
// 96 cols each; 256 blocks = 1/CU; x read once; W re-read from L2.
// Floor: HBM ~108 MB = 17 us; L2 W-stream ~9 us/XCD; MFMA 7 us.

typedef unsigned short u16;
typedef __attribute__((ext_vector_type(8))) short short8;      // 16 B
typedef __attribute__((ext_vector_type(8))) _Float16 f16x8;    // 4 VGPR MFMA frag
typedef __attribute__((ext_vector_type(4))) float float4v;

__device__ inline u16 f16b(float f) {
  union { _Float16 h; u16 u; } v; v.h = (_Float16)f; return v.u;  // v_cvt_f16_f32 RNE
}

__device__ inline u16 f32_to_bf16(float f) {        // fallback path only
  union { float f; unsigned int u; } v; v.f = f;
  unsigned int r = v.u + 0x7FFF + ((v.u >> 16) & 1);
  return (u16)(r >> 16);
}

// ---------------- prep: W = Wo @ Wv, fp32 accum, f16 tiled ----------------
// wt layout for direct B-frag loads: element (o, h) at
//   wt[(h>>5)*24576 + o*32 + ((h>>3)&3)*8 + (h&7)]
// so a wave's frag load (16 cols x 4 q x 16B) is 1 KB contiguous.
// Same fma chain/k-order as r10/r11 (bit-identical W); adds register
// double-buffer prefetch of the Wv batch to hide L2 latency.
__global__ __launch_bounds__(256)
void prep_w(const float* __restrict__ Wv, const float* __restrict__ Wo,
            u16* __restrict__ wt) {
  __shared__ __align__(16) float wo[4][256];            // 4 KB
  const int og = blockIdx.x / 3, hc = blockIdx.x % 3;   // 192 o-grp x 3 h-chunk
  const int o0 = og * 4;
  ((float4v*)&wo[0][0])[threadIdx.x] =
      ((const float4v*)(Wo + (size_t)o0 * 256))[threadIdx.x];
  __syncthreads();
  const int h = hc * 256 + threadIdx.x;
  float acc[4] = {0.f, 0.f, 0.f, 0.f};
  float wvA[8], wvB[8];
#pragma unroll
  for (int u = 0; u < 8; ++u) wvA[u] = Wv[(size_t)u * 768 + h];

#define PFMA(wv_, kk_)                                                       \
  _Pragma("unroll")                                                          \
  for (int j = 0; j < 4; ++j) {                                              \
    float4v c0 = *(const float4v*)(&wo[j][kk_]);                             \
    float4v c1 = *(const float4v*)(&wo[j][(kk_) + 4]);                       \
    acc[j] = fmaf(c0[0], wv_[0], acc[j]);                                    \
    acc[j] = fmaf(c0[1], wv_[1], acc[j]);                                    \
    acc[j] = fmaf(c0[2], wv_[2], acc[j]);                                    \
    acc[j] = fmaf(c0[3], wv_[3], acc[j]);                                    \
    acc[j] = fmaf(c1[0], wv_[4], acc[j]);                                    \
    acc[j] = fmaf(c1[1], wv_[5], acc[j]);                                    \
    acc[j] = fmaf(c1[2], wv_[6], acc[j]);                                    \
    acc[j] = fmaf(c1[3], wv_[7], acc[j]);                                    \
  }

  for (int k = 0; k < 240; k += 16) {
#pragma unroll
    for (int u = 0; u < 8; ++u) wvB[u] = Wv[(size_t)(k + 8 + u) * 768 + h];
    PFMA(wvA, k)
#pragma unroll
    for (int u = 0; u < 8; ++u) wvA[u] = Wv[(size_t)(k + 16 + u) * 768 + h];
    PFMA(wvB, k + 8)
  }
#pragma unroll
  for (int u = 0; u < 8; ++u) wvB[u] = Wv[(size_t)(248 + u) * 768 + h];
  PFMA(wvA, 240)
  PFMA(wvB, 248)
#undef PFMA

  const int kt = h >> 5, qq = (h >> 3) & 3, e = h & 7;
#pragma unroll
  for (int j = 0; j < 4; ++j)
    wt[(size_t)kt * 24576 + (o0 + j) * 32 + qq * 8 + e] = f16b(acc[j]);
}

// ---------------- main: out[16384,768] = x @ W^T, zero-barrier loop -------
// Block: 512 thr / 8 waves; 64 rows x 768 cols; wave w owns cols w*96..+95.
// LDS: x stripe as f16 [64][96 chunks of 8], chunk stored at c^(row&7)
// (frag reads 2-way max = free; staging b128 writes at the b128 floor).
__global__ __launch_bounds__(512, 2)
void gemm_xw(const float* __restrict__ x, const u16* __restrict__ wt,
             float* __restrict__ out) {
  __shared__ __align__(16) u16 S[64 * 768];       // 96 KB -> 1 block/CU

  const int tid = threadIdx.x;
  const int w = tid >> 6, l = tid & 63;
  const int q = l >> 4, mr = l & 15;
  const int row0 = blockIdx.x * 64;

  // ---- stage x[64][768] fp32 -> LDS f16, chunk-swizzled, ONCE ----
  {
    const int sr = ((w & 3) << 4) + mr;           // row 0..63 (2 waves/row-set)
    const int half = w >> 2;                      // even/odd chunk quads
    const float* gr = x + (size_t)(row0 + sr) * 768;
    u16* lr = S + sr * 768;
    const int key = sr & 7;
#pragma unroll
    for (int j = 0; j < 12; ++j) {
      const int c = q + 4 * (2 * j + half);       // chunk 0..95
      float4v v0 = *(const float4v*)(gr + c * 8);
      float4v v1 = *(const float4v*)(gr + c * 8 + 4);
      union { u16 h[8]; short8 s; } p;
#pragma unroll
      for (int e = 0; e < 4; ++e) { p.h[e] = f16b(v0[e]); p.h[e + 4] = f16b(v1[e]); }
      *(short8*)(lr + ((c ^ key) << 3)) = p.s;
    }
  }
  __syncthreads();                                // the ONLY barrier

  // B-frag lane base: wt + (col)*32 + q*8, col = w*96 + jn*16 + mr
  const u16* wl = wt + (w * 96 + mr) * 32 + q * 8;
  const int akey = (mr & 7);

  float4v acc[4][6];
#pragma unroll
  for (int i = 0; i < 4; ++i)
#pragma unroll
    for (int j = 0; j < 6; ++j) acc[i][j] = (float4v){0.f, 0.f, 0.f, 0.f};

  f16x8 a0[4], a1[4], b0[6], b1[6];

#define LDA(av_, kt_)                                                        \
  _Pragma("unroll")                                                          \
  for (int im = 0; im < 4; ++im)                                             \
    av_[im] = *(const f16x8*)(                                               \
        &S[(im * 16 + mr) * 768 + ((((kt_) * 4 + q) ^ akey) << 3)]);

#define LDB(bv_, kt_)                                                        \
  { const u16* gp = wl + (size_t)(kt_) * 24576;                              \
    _Pragma("unroll")                                                        \
    for (int jn = 0; jn < 6; ++jn)                                           \
      bv_[jn] = *(const f16x8*)(gp + jn * 512); }

#define MM(av_, bv_)                                                         \
  { __builtin_amdgcn_s_setprio(1);                                           \
    _Pragma("unroll")                                                        \
    for (int im = 0; im < 4; ++im)                                           \
      _Pragma("unroll")                                                      \
      for (int jn = 0; jn < 6; ++jn)                                         \
        acc[im][jn] = __builtin_amdgcn_mfma_f32_16x16x32_f16(                \
            av_[im], bv_[jn], acc[im][jn], 0, 0, 0);                         \
    __builtin_amdgcn_s_setprio(0); }

  LDB(b0, 0)
  LDA(a0, 0)
  for (int kt = 0; kt < 22; kt += 2) {
    LDB(b1, kt + 1)
    LDA(a1, kt + 1)
    MM(a0, b0)
    LDB(b0, kt + 2)
    LDA(a0, kt + 2)
    MM(a1, b1)
  }
  LDB(b1, 23)
  LDA(a1, 23)
  MM(a0, b0)
  MM(a1, b1)

#undef LDA
#undef LDB
#undef MM

  // ---- epilogue: C/D col=lane&15, row=q*4+reg (m89-verified) ----
#pragma unroll
  for (int im = 0; im < 4; ++im)
#pragma unroll
    for (int jn = 0; jn < 6; ++jn) {
      const int r0 = row0 + im * 16 + q * 4;
      const int c  = w * 96 + jn * 16 + mr;
#pragma unroll
      for (int r = 0; r < 4; ++r)
        out[(size_t)(r0 + r) * 768 + c] = acc[im][jn][r];
    }
}

// ---------------- fallback (no workspace): verified r7 kernel ----------------
__global__ __launch_bounds__(512, 1)
void fused_fallback(const float* __restrict__ x,
                    const float* __restrict__ Wv, const float* __restrict__ Wo,
                    float* __restrict__ out) {
  __shared__ __align__(16) u16 As[64 * 32];
  __shared__ __align__(16) u16 Bs[256 * 32];
  __shared__ __align__(16) u16 Vs[64 * 264];

  const int tid = threadIdx.x;
  const int w  = tid >> 6, l = tid & 63;
  const int q  = l >> 4, mr = l & 15;
  const int wm = w & 1, wn = w >> 1;
  const int row0 = blockIdx.x * 64;
  const int xr = tid >> 3, xg = (tid & 7) * 4;
  const int wr = tid >> 1, wh = (tid & 1) * 16;

  float4v acc[2][4];
#pragma unroll
  for (int i = 0; i < 2; ++i)
#pragma unroll
    for (int j = 0; j < 4; ++j) acc[i][j] = (float4v){0.f, 0.f, 0.f, 0.f};

  for (int kt = 0; kt < 24; ++kt) {
    const int k0 = kt * 32;
    {
      float4v v = *(const float4v*)(x + (size_t)(row0 + xr) * 768 + k0 + xg);
      union { u16 h[4]; uint2 u; } p;
      p.h[0] = f32_to_bf16(v[0]); p.h[1] = f32_to_bf16(v[1]);
      p.h[2] = f32_to_bf16(v[2]); p.h[3] = f32_to_bf16(v[3]);
      *(uint2*)(As + xr * 32 + xg) = p.u;
    }
    {
      const float* g = Wv + (size_t)wr * 768 + k0 + wh;
      union { u16 h[16]; short8 s[2]; } p;
#pragma unroll
      for (int u = 0; u < 4; ++u) {
        float4v v = *(const float4v*)(g + u * 4);
        p.h[u * 4 + 0] = f32_to_bf16(v[0]); p.h[u * 4 + 1] = f32_to_bf16(v[1]);
        p.h[u * 4 + 2] = f32_to_bf16(v[2]); p.h[u * 4 + 3] = f32_to_bf16(v[3]);
      }
      *(short8*)(Bs + wr * 32 + wh) = p.s[0];
      *(short8*)(Bs + wr * 32 + wh + 8) = p.s[1];
    }
    __syncthreads();

    short8 a[2], b[4];
#pragma unroll
    for (int i = 0; i < 2; ++i)
      a[i] = *(const short8*)(As + (wm * 32 + i * 16 + mr) * 32 + q * 8);
#pragma unroll
    for (int j = 0; j < 4; ++j)
      b[j] = *(const short8*)(Bs + (wn * 64 + j * 16 + mr) * 32 + q * 8);
#pragma unroll
    for (int i = 0; i < 2; ++i)
#pragma unroll
      for (int j = 0; j < 4; ++j)
        acc[i][j] = __builtin_amdgcn_mfma_f32_16x16x32_bf16(a[i], b[j], acc[i][j], 0, 0, 0);
    __syncthreads();
  }

#pragma unroll
  for (int i = 0; i < 2; ++i)
#pragma unroll
    for (int j = 0; j < 4; ++j) {
      int row = wm * 32 + i * 16 + q * 4;
      int col = wn * 64 + j * 16 + mr;
#pragma unroll
      for (int r = 0; r < 4; ++r)
        Vs[(row + r) * 264 + col] = f32_to_bf16(acc[i][j][r]);
    }
  __syncthreads();

  for (int c = 0; c < 3; ++c) {
    float4v acc2[2][4];
#pragma unroll
    for (int i = 0; i < 2; ++i)
#pragma unroll
      for (int j = 0; j < 4; ++j) acc2[i][j] = (float4v){0.f, 0.f, 0.f, 0.f};

    for (int kt = 0; kt < 8; ++kt) {
      const int k0 = kt * 32;
      {
        const float* g = Wo + (size_t)(c * 256 + wr) * 256 + k0 + wh;
        union { u16 h[16]; short8 s[2]; } p;
#pragma unroll
        for (int u = 0; u < 4; ++u) {
          float4v v = *(const float4v*)(g + u * 4);
          p.h[u * 4 + 0] = f32_to_bf16(v[0]); p.h[u * 4 + 1] = f32_to_bf16(v[1]);
          p.h[u * 4 + 2] = f32_to_bf16(v[2]); p.h[u * 4 + 3] = f32_to_bf16(v[3]);
        }
        *(short8*)(Bs + wr * 32 + wh) = p.s[0];
        *(short8*)(Bs + wr * 32 + wh + 8) = p.s[1];
      }
      __syncthreads();

      short8 a[2], b[4];
#pragma unroll
      for (int i = 0; i < 2; ++i)
        a[i] = *(const short8*)(Vs + (wm * 32 + i * 16 + mr) * 264 + k0 + q * 8);
#pragma unroll
      for (int j = 0; j < 4; ++j)
        b[j] = *(const short8*)(Bs + (wn * 64 + j * 16 + mr) * 32 + q * 8);
#pragma unroll
      for (int i = 0; i < 2; ++i)
#pragma unroll
        for (int j = 0; j < 4; ++j)
          acc2[i][j] = __builtin_amdgcn_mfma_f32_16x16x32_bf16(a[i], b[j], acc2[i][j], 0, 0, 0);
      __syncthreads();
    }

#pragma unroll
    for (int i = 0; i < 2; ++i)
#pragma unroll
      for (int j = 0; j < 4; ++j) {
        int row = row0 + wm * 32 + i * 16 + q * 4;
        int col = c * 256 + wn * 64 + j * 16 + mr;
#pragma unroll
        for (int r = 0; r < 4; ++r)
          out[(size_t)(row + r) * 768 + col] = acc2[i][j][r];
      }
  }
}

extern "C" void kernel_launch(void* const* d_in, const int* in_sizes, int n_in,
                              void* d_out, int out_size, void* d_ws, size_t ws_size,
                              hipStream_t stream) {
  (void)in_sizes; (void)n_in; (void)out_size;
  const float* x  = (const float*)d_in[0];  // [16384, 768]
  const float* Wv = (const float*)d_in[3];  // [256, 768]
  const float* Wo = (const float*)d_in[4];  // [768, 256]
  float* out = (float*)d_out;

  if (ws_size >= (size_t)768 * 768 * 2) {   // 1.18 MB f16 combined weight
    u16* wt = (u16*)d_ws;
    prep_w<<<dim3(576), dim3(256), 0, stream>>>(Wv, Wo, wt);
    gemm_xw<<<dim3(256), dim3(512), 0, stream>>>(x, wt, out);
  } else {
    fused_fallback<<<dim3(256), dim3(512), 0, stream>>>(x, Wv, Wo, out);
  }
}